// Round 8
// baseline (152.187 us; speedup 1.0000x reference)
//
#include <hip/hip_runtime.h>
#include <hip/hip_fp16.h>

#define N_NODES 50000
#define N_EDGES 800000
#define D_FEAT  64
#define BSHIFT  6
#define NBKT    782               // ceil(50000/64) buckets of 64 nodes
#define PSHIFT  20
#define SRC_MASK ((1 << PSHIFT) - 1)   // src < 50000 < 2^20
#define BCAP    2048              // fixed PAIR slots per bucket; load ~ Poisson(1024)

// K1 config: 391 blocks x 512 threads, 2047 edges/block (391*2047 >= 800000)
#define K1_NB    391
#define K1_TH    512
#define K1_CHUNK 2047
// TOT counters padded to one cacheline to avoid same-line atomic serialization
#define TOTSTRIDE 16

// K2: 4 feature-quarters x 782 buckets; quarter pinned to XCD pair via blockIdx&7
#define K2_NB (391 * 8)

// ---------- workspace layout (ints) ----------
#define WS_TOT    0                               // padded bucket counters [NBKT*16]
#define WS_OVFC   (NBKT * TOTSTRIDE)              // overflow counter [1] (+pad)
#define WS_PAIR   (WS_OVFC + 16)                  // fixed regions [NBKT*BCAP]
#define WS_OVF    (WS_PAIR + NBKT * BCAP)         // overflow (dst,src) [2*N_EDGES]
#define WS_PACKED (WS_OVF + 2 * N_EDGES)          // __half2[N_NODES*D_FEAT]
#define WS_INTS   (WS_PACKED + N_NODES * D_FEAT)

__device__ inline void detect_idx_layout(const int* idx, int* flag) {
    int allzero = 1;
    #pragma unroll
    for (int i = 1; i < 129; i += 2) {
        if (idx[i] != 0) allzero = 0;
    }
    *flag = allzero;
}

// ============ K1: fused pack + hist + claim + clustered scatter (unchanged) ============
__global__ __launch_bounds__(K1_TH) void front(int* __restrict__ W,
                                               const int* __restrict__ idx,
                                               const float* __restrict__ xs,
                                               const float* __restrict__ xp) {
    __shared__ int h[NBKT];          // hist -> claim base -> scatter cursor
    __shared__ int flg_s;
    const int t = threadIdx.x;
    for (int i = t; i < NBKT; i += K1_TH) h[i] = 0;
    if (t == 0) flg_s = 1;
    __syncthreads();
    if (t < 128 && idx[2 * t + 1] != 0) flg_s = 0;   // parallel int64 detect
    __syncthreads();
    const int flg = flg_s;

    // stash this block's edges in registers + LDS bucket hist
    const int ebase = blockIdx.x * K1_CHUNK;
    const int eend  = min(ebase + K1_CHUNK, N_EDGES);
    int src_r[4], dst_r[4];
    #pragma unroll
    for (int i = 0; i < 4; ++i) {
        int e = ebase + t + i * K1_TH;
        bool v = (e < eend);
        int s = 0, d = 0;
        if (v) {
            if (flg) {
                s = ((const int2*)idx)[e].x;
                d = ((const int2*)idx)[N_EDGES + e].x;
            } else {
                s = idx[e];
                d = idx[N_EDGES + e];
            }
            atomicAdd(&h[d >> BSHIFT], 1);
        }
        src_r[i] = v ? s : -1;
        dst_r[i] = d;
    }

    // pack features fp16-interleaved (independent work; overlaps hist latency)
    {
        const float4* xs4 = (const float4*)xs;
        const float4* xp4 = (const float4*)xp;
        uint4* pk4 = (uint4*)(W + WS_PACKED);
        const int gtid = blockIdx.x * K1_TH + t;
        for (int g = gtid; g < (N_NODES * D_FEAT) / 4; g += K1_NB * K1_TH) {
            float4 a = xs4[g], p = xp4[g];
            union { __half2 h2; unsigned int u; } c0, c1, c2, c3;
            c0.h2 = __floats2half2_rn(a.x, p.x);
            c1.h2 = __floats2half2_rn(a.y, p.y);
            c2.h2 = __floats2half2_rn(a.z, p.z);
            c3.h2 = __floats2half2_rn(a.w, p.w);
            pk4[g] = make_uint4(c0.u, c1.u, c2.u, c3.u);
        }
    }
    __syncthreads();

    // claim contiguous within-bucket ranges (padded counters: 1 line each)
    for (int j = t; j < NBKT; j += K1_TH) {
        int c = h[j];
        h[j] = (c > 0) ? atomicAdd(&W[WS_TOT + j * TOTSTRIDE], c) : 0;
    }
    __syncthreads();

    // scatter from regs into fixed bucket regions — clustered writes
    #pragma unroll
    for (int i = 0; i < 4; ++i) {
        if (src_r[i] >= 0) {
            int d = dst_r[i];
            int bkt = d >> BSHIFT;
            int pos = atomicAdd(&h[bkt], 1);
            if (pos < BCAP) {
                W[WS_PAIR + bkt * BCAP + pos] = src_r[i] | ((d & 63) << PSHIFT);
            } else {                 // statistically unreachable; fully correct
                int op = atomicAdd(&W[WS_OVFC], 1);
                W[WS_OVF + 2 * op]     = d;
                W[WS_OVF + 2 * op + 1] = src_r[i];
            }
        }
    }
}

// ============ K2: per-(bucket,quarter) LDS sort + L2-resident gather ============
// blockIdx & 7 -> XCD slot (round-robin dispatch): quarter q = slot>>1 pinned to
// XCD pair {2q,2q+1}; per-XCD gather working set = 12.8MB/4 = 3.2MB < 4MB L2.
__global__ __launch_bounds__(512) void sort_gather_q(const int* __restrict__ W,
                                                     float* __restrict__ out) {
    __shared__ int pair_l[BCAP];     // 8 KB
    __shared__ int ssrc_l[BCAP];     // 8 KB
    __shared__ int h64[64];
    __shared__ int noff[65];
    const int t = threadIdx.x;
    const int xslot = blockIdx.x & 7;
    const int q = xslot >> 1;                              // feature quarter 0..3
    const int b = ((blockIdx.x >> 3) << 1) | (xslot & 1);  // bucket 0..781
    const int nedge = min(W[WS_TOT + b * TOTSTRIDE], BCAP);
    const int pbase = WS_PAIR + b * BCAP;

    // ---- counting sort of this bucket (duplicated per quarter; LDS-only) ----
    if (t < 64) h64[t] = 0;
    __syncthreads();
    for (int e = t; e < nedge; e += 512) {
        int v = W[pbase + e];
        pair_l[e] = v;
        atomicAdd(&h64[(unsigned)v >> PSHIFT], 1);
    }
    __syncthreads();
    if (t < 64) {
        int c = h64[t];
        int incl = c;
        #pragma unroll
        for (int off = 1; off < 64; off <<= 1) {
            int u = __shfl_up(incl, off, 64);
            if (t >= off) incl += u;
        }
        noff[t] = incl - c;
        if (t == 63) noff[64] = incl;
        h64[t] = incl - c;           // local cursor
    }
    __syncthreads();
    for (int e = t; e < nedge; e += 512) {
        int v = pair_l[e];
        int p = atomicAdd(&h64[(unsigned)v >> PSHIFT], 1);
        ssrc_l[p] = v & SRC_MASK;
    }
    __syncthreads();

    // ---- gather: lane = (edge-slot 0..3)<<4 | feat 0..15 ----
    const __half2* packed = (const __half2*)(W + WS_PACKED);
    const int wave = t >> 6;
    const int lane = t & 63;
    const int eg   = lane >> 4;          // edge slot within group of 4
    const int fcol = (q << 4) + (lane & 15);   // half2 column 0..63

    for (int nn = wave; nn < 64; nn += 8) {
        const int node = (b << BSHIFT) + nn;
        if (node >= N_NODES) break;      // tail of bucket 781 only; nn monotone
        int beg = __builtin_amdgcn_readfirstlane(noff[nn]);
        int end = __builtin_amdgcn_readfirstlane(noff[nn + 1]);

        float s0 = 0.f, s1 = 0.f, p0 = 1.f, p1 = 1.f;
        int i = beg;
        for (; i + 7 < end; i += 8) {    // 8 edges: 2 groups of 4, ILP pair
            int a0 = ssrc_l[i + eg];
            int a1 = ssrc_l[i + 4 + eg];
            float2 f0 = __half22float2(packed[a0 * D_FEAT + fcol]);
            float2 f1 = __half22float2(packed[a1 * D_FEAT + fcol]);
            s0 += f0.x; s1 += f1.x;
            p0 *= f0.y; p1 *= f1.y;
        }
        for (; i + 3 < end; i += 4) {    // one full group of 4
            int a0 = ssrc_l[i + eg];
            float2 f0 = __half22float2(packed[a0 * D_FEAT + fcol]);
            s0 += f0.x;
            p0 *= f0.y;
        }
        if (i < end) {                   // ragged tail, predicated
            int e = i + eg;
            bool v = (e < end);
            int a = ssrc_l[v ? e : i];
            float2 f = __half22float2(packed[a * D_FEAT + fcol]);
            s0 += v ? f.x : 0.f;
            p0 *= v ? f.y : 1.f;
        }
        float s = s0 + s1;
        float p = p0 * p1;
        s += __shfl_xor(s, 16, 64);  p *= __shfl_xor(p, 16, 64);
        s += __shfl_xor(s, 32, 64);  p *= __shfl_xor(p, 32, 64);
        if (eg == 0) {                   // lanes 0..15 write this quarter
            out[(long)node * D_FEAT + fcol] = s;
            out[(long)N_NODES * D_FEAT + (long)node * D_FEAT + fcol] = p;
        }
    }

    // overflow tail (empty in practice; correct if not)
    int novf = W[WS_OVFC];
    if (novf > 0) {
        __syncthreads();
        for (int k = wave; k < novf; k += 8) {
            int d = W[WS_OVF + 2 * k];
            if ((d >> BSHIFT) == b && eg == 0) {
                int s = W[WS_OVF + 2 * k + 1];
                float2 f = __half22float2(packed[s * D_FEAT + fcol]);
                atomicAdd(out + (long)d * D_FEAT + fcol, f.x);
                unsigned int* ua =
                    (unsigned int*)(out + (long)N_NODES * D_FEAT + (long)d * D_FEAT + fcol);
                unsigned int old = __hip_atomic_load(ua, __ATOMIC_RELAXED,
                                                     __HIP_MEMORY_SCOPE_AGENT);
                while (true) {
                    unsigned int assumed = old;
                    unsigned int desired =
                        __float_as_uint(__uint_as_float(assumed) * f.y);
                    old = atomicCAS(ua, assumed, desired);
                    if (old == assumed) break;
                }
            }
        }
    }
}

// ---------------- atomic fallback path, used only if ws is too small ----------------
__device__ inline void atomicMulF32(float* addr, float val) {
    unsigned int* ua = (unsigned int*)addr;
    unsigned int old = __hip_atomic_load(ua, __ATOMIC_RELAXED, __HIP_MEMORY_SCOPE_AGENT);
    while (true) {
        unsigned int assumed = old;
        unsigned int desired = __float_as_uint(__uint_as_float(assumed) * val);
        old = atomicCAS(ua, assumed, desired);
        if (old == assumed) break;
    }
}

__global__ void fb_init(float* __restrict__ out, int* __restrict__ flag,
                        const int* __restrict__ idx) {
    const int n4 = (N_NODES * D_FEAT) / 4;
    int tid = blockIdx.x * blockDim.x + threadIdx.x;
    int stride = gridDim.x * blockDim.x;
    float4* o = (float4*)out;
    const float4 z = make_float4(0.f, 0.f, 0.f, 0.f);
    const float4 one = make_float4(1.f, 1.f, 1.f, 1.f);
    for (int i = tid; i < n4; i += stride) { o[i] = z; o[n4 + i] = one; }
    if (blockIdx.x == 0 && threadIdx.x == 0) detect_idx_layout(idx, flag);
}

__global__ void fb_scatter(const float* __restrict__ xs, const float* __restrict__ xp,
                           const int* __restrict__ idx, float* __restrict__ out,
                           const int* __restrict__ flag) {
    long tid = (long)blockIdx.x * blockDim.x + threadIdx.x;
    const long total = (long)N_EDGES * (D_FEAT / 4);
    if (tid >= total) return;
    int e = (int)(tid >> 4);
    int c = (int)(tid & 15);
    int src, dst;
    if (*flag) { src = idx[2 * e]; dst = idx[2 * (N_EDGES + e)]; }
    else       { src = idx[e];     dst = idx[N_EDGES + e]; }
    const float4 s = ((const float4*)(xs + (long)src * D_FEAT))[c];
    const float4 p = ((const float4*)(xp + (long)src * D_FEAT))[c];
    float* os = out + (long)dst * D_FEAT + c * 4;
    float* op = out + (long)N_NODES * D_FEAT + (long)dst * D_FEAT + c * 4;
    atomicAdd(os + 0, s.x); atomicAdd(os + 1, s.y);
    atomicAdd(os + 2, s.z); atomicAdd(os + 3, s.w);
    atomicMulF32(op + 0, p.x); atomicMulF32(op + 1, p.y);
    atomicMulF32(op + 2, p.z); atomicMulF32(op + 3, p.w);
}

extern "C" void kernel_launch(void* const* d_in, const int* in_sizes, int n_in,
                              void* d_out, int out_size, void* d_ws, size_t ws_size,
                              hipStream_t stream) {
    const float* x_sum  = (const float*)d_in[0];
    const float* x_prod = (const float*)d_in[1];
    const int*   eidx   = (const int*)d_in[2];
    float* out = (float*)d_out;
    int* W = (int*)d_ws;

    if (ws_size < (size_t)WS_INTS * sizeof(int)) {
        fb_init<<<1024, 256, 0, stream>>>(out, W, eidx);
        const long total = (long)N_EDGES * (D_FEAT / 4);
        int grid = (int)((total + 255) / 256);
        fb_scatter<<<grid, 256, 0, stream>>>(x_sum, x_prod, eidx, out, W);
        return;
    }

    // zero padded bucket counters + overflow counter (~50 KB)
    hipMemsetAsync(W, 0, (size_t)(WS_OVFC + 16) * sizeof(int), stream);
    front<<<K1_NB, K1_TH, 0, stream>>>(W, eidx, x_sum, x_prod);
    sort_gather_q<<<K2_NB, 512, 0, stream>>>(W, out);
}

// Round 10
// 147.869 us; speedup vs baseline: 1.0292x; 1.0292x over previous
//
#include <hip/hip_runtime.h>
#include <hip/hip_fp16.h>

#define N_NODES 50000
#define N_EDGES 800000
#define D_FEAT  64
#define BSHIFT  6
#define NBKT    782               // ceil(50000/64) buckets of 64 nodes
#define PSHIFT  20
#define SRC_MASK ((1 << PSHIFT) - 1)   // src < 50000 < 2^20
#define BCAP    2048              // fixed PAIR slots per bucket; load ~ Poisson(1024)

// K1 config: 782 blocks x 512 threads, 1024 edges/block (782*1024 >= 800000)
// -> 3 blocks/CU, ~24 waves/CU (vs 391-block config's 12) for the latency-bound
//    edge binning phase.
#define K1_NB    782
#define K1_TH    512
#define K1_CHUNK 1024
#define K1_EPT   2                // edge regs per thread
// TOT counters padded to one cacheline to avoid same-line atomic serialization
#define TOTSTRIDE 16

// ---------- workspace layout (ints) ----------
#define WS_TOT    0                               // padded bucket counters [NBKT*16]
#define WS_OVFC   (NBKT * TOTSTRIDE)              // overflow counter [1] (+pad)
#define WS_PAIR   (WS_OVFC + 16)                  // fixed regions [NBKT*BCAP]
#define WS_OVF    (WS_PAIR + NBKT * BCAP)         // overflow (dst,src) [2*N_EDGES]
#define WS_PACKED (WS_OVF + 2 * N_EDGES)          // __half2[N_NODES*D_FEAT]
#define WS_INTS   (WS_PACKED + N_NODES * D_FEAT)

__device__ inline void detect_idx_layout(const int* idx, int* flag) {
    int allzero = 1;
    #pragma unroll
    for (int i = 1; i < 129; i += 2) {
        if (idx[i] != 0) allzero = 0;
    }
    *flag = allzero;
}

// ============ K1: fused pack + hist + claim + clustered scatter ============
__global__ __launch_bounds__(K1_TH) void front(int* __restrict__ W,
                                               const int* __restrict__ idx,
                                               const float* __restrict__ xs,
                                               const float* __restrict__ xp) {
    __shared__ int h[NBKT];          // hist -> claim base -> scatter cursor
    __shared__ int flg_s;
    const int t = threadIdx.x;
    for (int i = t; i < NBKT; i += K1_TH) h[i] = 0;
    if (t == 0) flg_s = 1;
    __syncthreads();
    if (t < 128 && idx[2 * t + 1] != 0) flg_s = 0;   // parallel int64 detect
    __syncthreads();
    const int flg = flg_s;

    // stash this block's edges in registers + LDS bucket hist
    const int ebase = blockIdx.x * K1_CHUNK;
    const int eend  = min(ebase + K1_CHUNK, N_EDGES);
    int src_r[K1_EPT], dst_r[K1_EPT];
    #pragma unroll
    for (int i = 0; i < K1_EPT; ++i) {
        int e = ebase + t + i * K1_TH;
        bool v = (e < eend);
        int s = 0, d = 0;
        if (v) {
            if (flg) {
                s = ((const int2*)idx)[e].x;
                d = ((const int2*)idx)[N_EDGES + e].x;
            } else {
                s = idx[e];
                d = idx[N_EDGES + e];
            }
            atomicAdd(&h[d >> BSHIFT], 1);
        }
        src_r[i] = v ? s : -1;
        dst_r[i] = d;
    }

    // pack features fp16-interleaved (independent work; overlaps hist latency)
    {
        const float4* xs4 = (const float4*)xs;
        const float4* xp4 = (const float4*)xp;
        uint4* pk4 = (uint4*)(W + WS_PACKED);
        const int gtid = blockIdx.x * K1_TH + t;
        for (int g = gtid; g < (N_NODES * D_FEAT) / 4; g += K1_NB * K1_TH) {
            float4 a = xs4[g], p = xp4[g];
            union { __half2 h2; unsigned int u; } c0, c1, c2, c3;
            c0.h2 = __floats2half2_rn(a.x, p.x);
            c1.h2 = __floats2half2_rn(a.y, p.y);
            c2.h2 = __floats2half2_rn(a.z, p.z);
            c3.h2 = __floats2half2_rn(a.w, p.w);
            pk4[g] = make_uint4(c0.u, c1.u, c2.u, c3.u);
        }
    }
    __syncthreads();

    // claim contiguous within-bucket ranges (padded counters: 1 line each)
    for (int j = t; j < NBKT; j += K1_TH) {
        int c = h[j];
        h[j] = (c > 0) ? atomicAdd(&W[WS_TOT + j * TOTSTRIDE], c) : 0;
    }
    __syncthreads();

    // scatter from regs into fixed bucket regions — clustered writes
    #pragma unroll
    for (int i = 0; i < K1_EPT; ++i) {
        if (src_r[i] >= 0) {
            int d = dst_r[i];
            int bkt = d >> BSHIFT;
            int pos = atomicAdd(&h[bkt], 1);
            if (pos < BCAP) {
                W[WS_PAIR + bkt * BCAP + pos] = src_r[i] | ((d & 63) << PSHIFT);
            } else {                 // statistically unreachable; fully correct
                int op = atomicAdd(&W[WS_OVFC], 1);
                W[WS_OVF + 2 * op]     = d;
                W[WS_OVF + 2 * op + 1] = src_r[i];
            }
        }
    }
}

// ============ K2: per-bucket LDS counting sort + gather/reduce (R4-proven) ============
__global__ __launch_bounds__(512) void sort_gather(const int* __restrict__ W,
                                                   float* __restrict__ out) {
    __shared__ int pair_l[BCAP];     // 8 KB
    __shared__ int ssrc_l[BCAP];     // 8 KB
    __shared__ int h64[64];
    __shared__ int noff[65];
    const int b = blockIdx.x;
    const int t = threadIdx.x;
    const int nedge = min(W[WS_TOT + b * TOTSTRIDE], BCAP);
    const int pbase = WS_PAIR + b * BCAP;

    if (t < 64) h64[t] = 0;
    __syncthreads();
    for (int e = t; e < nedge; e += 512) {
        int v = W[pbase + e];
        pair_l[e] = v;
        atomicAdd(&h64[(unsigned)v >> PSHIFT], 1);
    }
    __syncthreads();
    if (t < 64) {
        int c = h64[t];
        int incl = c;
        #pragma unroll
        for (int off = 1; off < 64; off <<= 1) {
            int u = __shfl_up(incl, off, 64);
            if (t >= off) incl += u;
        }
        noff[t] = incl - c;
        if (t == 63) noff[64] = incl;
        h64[t] = incl - c;           // local cursor
    }
    __syncthreads();
    for (int e = t; e < nedge; e += 512) {
        int v = pair_l[e];
        int p = atomicAdd(&h64[(unsigned)v >> PSHIFT], 1);
        ssrc_l[p] = v & SRC_MASK;
    }
    __syncthreads();

    const __half2* packed = (const __half2*)(W + WS_PACKED);
    const int wave = t >> 6;
    const int lane = t & 63;
    for (int nn = wave; nn < 64; nn += 8) {
        const int node = (b << BSHIFT) + nn;
        if (node >= N_NODES) break;      // tail of bucket 781 only; nn monotone
        int beg = __builtin_amdgcn_readfirstlane(noff[nn]);
        int end = __builtin_amdgcn_readfirstlane(noff[nn + 1]);

        float s0 = 0.f, s1 = 0.f, s2 = 0.f, s3 = 0.f;
        float s4 = 0.f, s5 = 0.f, s6 = 0.f, s7 = 0.f;
        float p0 = 1.f, p1 = 1.f, p2 = 1.f, p3 = 1.f;
        float p4 = 1.f, p5 = 1.f, p6 = 1.f, p7 = 1.f;
        int i = beg;
        for (; i + 7 < end; i += 8) {
            int a0 = ssrc_l[i],     a1 = ssrc_l[i + 1];
            int a2 = ssrc_l[i + 2], a3 = ssrc_l[i + 3];
            int a4 = ssrc_l[i + 4], a5 = ssrc_l[i + 5];
            int a6 = ssrc_l[i + 6], a7 = ssrc_l[i + 7];
            float2 f0 = __half22float2(packed[a0 * D_FEAT + lane]);
            float2 f1 = __half22float2(packed[a1 * D_FEAT + lane]);
            float2 f2 = __half22float2(packed[a2 * D_FEAT + lane]);
            float2 f3 = __half22float2(packed[a3 * D_FEAT + lane]);
            float2 f4 = __half22float2(packed[a4 * D_FEAT + lane]);
            float2 f5 = __half22float2(packed[a5 * D_FEAT + lane]);
            float2 f6 = __half22float2(packed[a6 * D_FEAT + lane]);
            float2 f7 = __half22float2(packed[a7 * D_FEAT + lane]);
            s0 += f0.x; s1 += f1.x; s2 += f2.x; s3 += f3.x;
            s4 += f4.x; s5 += f5.x; s6 += f6.x; s7 += f7.x;
            p0 *= f0.y; p1 *= f1.y; p2 *= f2.y; p3 *= f3.y;
            p4 *= f4.y; p5 *= f5.y; p6 *= f6.y; p7 *= f7.y;
        }
        for (; i + 1 < end; i += 2) {
            int a0 = ssrc_l[i], a1 = ssrc_l[i + 1];
            float2 f0 = __half22float2(packed[a0 * D_FEAT + lane]);
            float2 f1 = __half22float2(packed[a1 * D_FEAT + lane]);
            s0 += f0.x; s1 += f1.x;
            p0 *= f0.y; p1 *= f1.y;
        }
        if (i < end) {
            float2 f = __half22float2(packed[ssrc_l[i] * D_FEAT + lane]);
            s0 += f.x;
            p0 *= f.y;
        }
        float ssum = ((s0 + s1) + (s2 + s3)) + ((s4 + s5) + (s6 + s7));
        float pprd = ((p0 * p1) * (p2 * p3)) * ((p4 * p5) * (p6 * p7));
        out[(long)node * D_FEAT + lane] = ssum;
        out[(long)N_NODES * D_FEAT + (long)node * D_FEAT + lane] = pprd;
    }

    // overflow tail (empty in practice; correct if not)
    int novf = W[WS_OVFC];
    if (novf > 0) {
        __syncthreads();
        for (int k = wave; k < novf; k += 8) {
            int d = W[WS_OVF + 2 * k];
            if ((d >> BSHIFT) == b) {
                int s = W[WS_OVF + 2 * k + 1];
                float2 f = __half22float2(packed[s * D_FEAT + lane]);
                atomicAdd(out + (long)d * D_FEAT + lane, f.x);
                unsigned int* ua =
                    (unsigned int*)(out + (long)N_NODES * D_FEAT + (long)d * D_FEAT + lane);
                unsigned int old = __hip_atomic_load(ua, __ATOMIC_RELAXED,
                                                     __HIP_MEMORY_SCOPE_AGENT);
                while (true) {
                    unsigned int assumed = old;
                    unsigned int desired =
                        __float_as_uint(__uint_as_float(assumed) * f.y);
                    old = atomicCAS(ua, assumed, desired);
                    if (old == assumed) break;
                }
            }
        }
    }
}

// ---------------- atomic fallback path, used only if ws is too small ----------------
__device__ inline void atomicMulF32(float* addr, float val) {
    unsigned int* ua = (unsigned int*)addr;
    unsigned int old = __hip_atomic_load(ua, __ATOMIC_RELAXED, __HIP_MEMORY_SCOPE_AGENT);
    while (true) {
        unsigned int assumed = old;
        unsigned int desired = __float_as_uint(__uint_as_float(assumed) * val);
        old = atomicCAS(ua, assumed, desired);
        if (old == assumed) break;
    }
}

__global__ void fb_init(float* __restrict__ out, int* __restrict__ flag,
                        const int* __restrict__ idx) {
    const int n4 = (N_NODES * D_FEAT) / 4;
    int tid = blockIdx.x * blockDim.x + threadIdx.x;
    int stride = gridDim.x * blockDim.x;
    float4* o = (float4*)out;
    const float4 z = make_float4(0.f, 0.f, 0.f, 0.f);
    const float4 one = make_float4(1.f, 1.f, 1.f, 1.f);
    for (int i = tid; i < n4; i += stride) { o[i] = z; o[n4 + i] = one; }
    if (blockIdx.x == 0 && threadIdx.x == 0) detect_idx_layout(idx, flag);
}

__global__ void fb_scatter(const float* __restrict__ xs, const float* __restrict__ xp,
                           const int* __restrict__ idx, float* __restrict__ out,
                           const int* __restrict__ flag) {
    long tid = (long)blockIdx.x * blockDim.x + threadIdx.x;
    const long total = (long)N_EDGES * (D_FEAT / 4);
    if (tid >= total) return;
    int e = (int)(tid >> 4);
    int c = (int)(tid & 15);
    int src, dst;
    if (*flag) { src = idx[2 * e]; dst = idx[2 * (N_EDGES + e)]; }
    else       { src = idx[e];     dst = idx[N_EDGES + e]; }
    const float4 s = ((const float4*)(xs + (long)src * D_FEAT))[c];
    const float4 p = ((const float4*)(xp + (long)src * D_FEAT))[c];
    float* os = out + (long)dst * D_FEAT + c * 4;
    float* op = out + (long)N_NODES * D_FEAT + (long)dst * D_FEAT + c * 4;
    atomicAdd(os + 0, s.x); atomicAdd(os + 1, s.y);
    atomicAdd(os + 2, s.z); atomicAdd(os + 3, s.w);
    atomicMulF32(op + 0, p.x); atomicMulF32(op + 1, p.y);
    atomicMulF32(op + 2, p.z); atomicMulF32(op + 3, p.w);
}

extern "C" void kernel_launch(void* const* d_in, const int* in_sizes, int n_in,
                              void* d_out, int out_size, void* d_ws, size_t ws_size,
                              hipStream_t stream) {
    const float* x_sum  = (const float*)d_in[0];
    const float* x_prod = (const float*)d_in[1];
    const int*   eidx   = (const int*)d_in[2];
    float* out = (float*)d_out;
    int* W = (int*)d_ws;

    if (ws_size < (size_t)WS_INTS * sizeof(int)) {
        fb_init<<<1024, 256, 0, stream>>>(out, W, eidx);
        const long total = (long)N_EDGES * (D_FEAT / 4);
        int grid = (int)((total + 255) / 256);
        fb_scatter<<<grid, 256, 0, stream>>>(x_sum, x_prod, eidx, out, W);
        return;
    }

    // zero padded bucket counters + overflow counter (~50 KB)
    hipMemsetAsync(W, 0, (size_t)(WS_OVFC + 16) * sizeof(int), stream);
    front<<<K1_NB, K1_TH, 0, stream>>>(W, eidx, x_sum, x_prod);
    sort_gather<<<NBKT, 512, 0, stream>>>(W, out);
}

// Round 11
// 139.798 us; speedup vs baseline: 1.0886x; 1.0577x over previous
//
#include <hip/hip_runtime.h>
#include <hip/hip_fp16.h>

#define N_NODES 50000
#define N_EDGES 800000
#define D_FEAT  64
#define BSHIFT  6
#define NBKT    782               // ceil(50000/64) buckets of 64 nodes
#define PSHIFT  20
#define SRC_MASK ((1 << PSHIFT) - 1)   // src < 50000 < 2^20
#define BCAP    2048              // fixed PAIR slots per bucket; load ~ Poisson(1024)

// K1 config: 391 blocks x 512 threads, 2047 edges/block (391*2047 >= 800000).
// R10 lesson: 782 blocks was 10us WORSE (per-block fixed overhead dominates).
#define K1_NB    391
#define K1_TH    512
#define K1_CHUNK 2047
// TOT counters padded to one cacheline to avoid same-line atomic serialization
#define TOTSTRIDE 16

// ---------- workspace layout (ints) ----------
#define WS_TOT    0                               // padded bucket counters [NBKT*16]
#define WS_OVFC   (NBKT * TOTSTRIDE)              // overflow counter [1] (+pad)
#define WS_PAIR   (WS_OVFC + 16)                  // fixed regions [NBKT*BCAP]
#define WS_OVF    (WS_PAIR + NBKT * BCAP)         // overflow (dst,src) [2*N_EDGES]
#define WS_PACKED (WS_OVF + 2 * N_EDGES)          // __half2[N_NODES*D_FEAT]
#define WS_INTS   (WS_PACKED + N_NODES * D_FEAT)

__device__ inline void detect_idx_layout(const int* idx, int* flag) {
    int allzero = 1;
    #pragma unroll
    for (int i = 1; i < 129; i += 2) {
        if (idx[i] != 0) allzero = 0;
    }
    *flag = allzero;
}

// ============ K1: pack + per-block LDS bucket lists + grouped flush ============
// Scatter line-waste fix: edges binned into per-bucket LDS linked lists; one
// flusher thread per bucket claims the range ONCE and writes its entries
// CONSECUTIVELY -> global write line-touches drop ~800K -> ~222K (51 -> 14 MB).
__global__ __launch_bounds__(K1_TH) void front(int* __restrict__ W,
                                               const int* __restrict__ idx,
                                               const float* __restrict__ xs,
                                               const float* __restrict__ xp) {
    __shared__ int head[NBKT];       // -1 terminated list heads
    __shared__ int nxt[K1_CHUNK];
    __shared__ int val[K1_CHUNK];    // src | dstlow<<20
    __shared__ int flg_s;
    const int t = threadIdx.x;
    for (int i = t; i < NBKT; i += K1_TH) head[i] = -1;
    if (t == 0) flg_s = 1;
    __syncthreads();
    if (t < 128 && idx[2 * t + 1] != 0) flg_s = 0;   // parallel int64 detect
    __syncthreads();
    const int flg = flg_s;

    // build lists: read edges, stash val in LDS, push onto bucket list
    const int ebase = blockIdx.x * K1_CHUNK;
    for (int k = t; k < K1_CHUNK; k += K1_TH) {
        int e = ebase + k;
        if (e < N_EDGES) {
            int s, d;
            if (flg) {
                s = ((const int2*)idx)[e].x;
                d = ((const int2*)idx)[N_EDGES + e].x;
            } else {
                s = idx[e];
                d = idx[N_EDGES + e];
            }
            val[k] = s | ((d & 63) << PSHIFT);
            nxt[k] = atomicExch(&head[d >> BSHIFT], k);
        }
    }

    // pack features fp16-interleaved (independent; overlaps LDS-list latency)
    {
        const float4* xs4 = (const float4*)xs;
        const float4* xp4 = (const float4*)xp;
        uint4* pk4 = (uint4*)(W + WS_PACKED);
        const int gtid = blockIdx.x * K1_TH + t;
        for (int g = gtid; g < (N_NODES * D_FEAT) / 4; g += K1_NB * K1_TH) {
            float4 a = xs4[g], p = xp4[g];
            union { __half2 h2; unsigned int u; } c0, c1, c2, c3;
            c0.h2 = __floats2half2_rn(a.x, p.x);
            c1.h2 = __floats2half2_rn(a.y, p.y);
            c2.h2 = __floats2half2_rn(a.z, p.z);
            c3.h2 = __floats2half2_rn(a.w, p.w);
            pk4[g] = make_uint4(c0.u, c1.u, c2.u, c3.u);
        }
    }
    __syncthreads();

    // flush: one thread per bucket — count, claim once, write consecutively
    for (int j = t; j < NBKT; j += K1_TH) {
        int c = 0;
        for (int i = head[j]; i >= 0; i = nxt[i]) ++c;
        if (c == 0) continue;
        int base = atomicAdd(&W[WS_TOT + j * TOTSTRIDE], c);
        int pos = base;
        for (int i = head[j]; i >= 0; i = nxt[i], ++pos) {
            int v = val[i];
            if (pos < BCAP) {
                W[WS_PAIR + j * BCAP + pos] = v;
            } else {                 // statistically unreachable; fully correct
                int op = atomicAdd(&W[WS_OVFC], 1);
                W[WS_OVF + 2 * op]     = (j << BSHIFT) | ((unsigned)v >> PSHIFT);
                W[WS_OVF + 2 * op + 1] = v & SRC_MASK;
            }
        }
    }
}

// ============ K2: per-bucket LDS counting sort + gather/reduce (R4-proven) ============
__global__ __launch_bounds__(512) void sort_gather(const int* __restrict__ W,
                                                   float* __restrict__ out) {
    __shared__ int pair_l[BCAP];     // 8 KB
    __shared__ int ssrc_l[BCAP];     // 8 KB
    __shared__ int h64[64];
    __shared__ int noff[65];
    const int b = blockIdx.x;
    const int t = threadIdx.x;
    const int nedge = min(W[WS_TOT + b * TOTSTRIDE], BCAP);
    const int pbase = WS_PAIR + b * BCAP;

    if (t < 64) h64[t] = 0;
    __syncthreads();
    for (int e = t; e < nedge; e += 512) {
        int v = W[pbase + e];
        pair_l[e] = v;
        atomicAdd(&h64[(unsigned)v >> PSHIFT], 1);
    }
    __syncthreads();
    if (t < 64) {
        int c = h64[t];
        int incl = c;
        #pragma unroll
        for (int off = 1; off < 64; off <<= 1) {
            int u = __shfl_up(incl, off, 64);
            if (t >= off) incl += u;
        }
        noff[t] = incl - c;
        if (t == 63) noff[64] = incl;
        h64[t] = incl - c;           // local cursor
    }
    __syncthreads();
    for (int e = t; e < nedge; e += 512) {
        int v = pair_l[e];
        int p = atomicAdd(&h64[(unsigned)v >> PSHIFT], 1);
        ssrc_l[p] = v & SRC_MASK;
    }
    __syncthreads();

    const __half2* packed = (const __half2*)(W + WS_PACKED);
    const int wave = t >> 6;
    const int lane = t & 63;
    for (int nn = wave; nn < 64; nn += 8) {
        const int node = (b << BSHIFT) + nn;
        if (node >= N_NODES) break;      // tail of bucket 781 only; nn monotone
        int beg = __builtin_amdgcn_readfirstlane(noff[nn]);
        int end = __builtin_amdgcn_readfirstlane(noff[nn + 1]);

        float s0 = 0.f, s1 = 0.f, s2 = 0.f, s3 = 0.f;
        float s4 = 0.f, s5 = 0.f, s6 = 0.f, s7 = 0.f;
        float p0 = 1.f, p1 = 1.f, p2 = 1.f, p3 = 1.f;
        float p4 = 1.f, p5 = 1.f, p6 = 1.f, p7 = 1.f;
        int i = beg;
        for (; i + 7 < end; i += 8) {
            int a0 = ssrc_l[i],     a1 = ssrc_l[i + 1];
            int a2 = ssrc_l[i + 2], a3 = ssrc_l[i + 3];
            int a4 = ssrc_l[i + 4], a5 = ssrc_l[i + 5];
            int a6 = ssrc_l[i + 6], a7 = ssrc_l[i + 7];
            float2 f0 = __half22float2(packed[a0 * D_FEAT + lane]);
            float2 f1 = __half22float2(packed[a1 * D_FEAT + lane]);
            float2 f2 = __half22float2(packed[a2 * D_FEAT + lane]);
            float2 f3 = __half22float2(packed[a3 * D_FEAT + lane]);
            float2 f4 = __half22float2(packed[a4 * D_FEAT + lane]);
            float2 f5 = __half22float2(packed[a5 * D_FEAT + lane]);
            float2 f6 = __half22float2(packed[a6 * D_FEAT + lane]);
            float2 f7 = __half22float2(packed[a7 * D_FEAT + lane]);
            s0 += f0.x; s1 += f1.x; s2 += f2.x; s3 += f3.x;
            s4 += f4.x; s5 += f5.x; s6 += f6.x; s7 += f7.x;
            p0 *= f0.y; p1 *= f1.y; p2 *= f2.y; p3 *= f3.y;
            p4 *= f4.y; p5 *= f5.y; p6 *= f6.y; p7 *= f7.y;
        }
        for (; i + 1 < end; i += 2) {
            int a0 = ssrc_l[i], a1 = ssrc_l[i + 1];
            float2 f0 = __half22float2(packed[a0 * D_FEAT + lane]);
            float2 f1 = __half22float2(packed[a1 * D_FEAT + lane]);
            s0 += f0.x; s1 += f1.x;
            p0 *= f0.y; p1 *= f1.y;
        }
        if (i < end) {
            float2 f = __half22float2(packed[ssrc_l[i] * D_FEAT + lane]);
            s0 += f.x;
            p0 *= f.y;
        }
        float ssum = ((s0 + s1) + (s2 + s3)) + ((s4 + s5) + (s6 + s7));
        float pprd = ((p0 * p1) * (p2 * p3)) * ((p4 * p5) * (p6 * p7));
        out[(long)node * D_FEAT + lane] = ssum;
        out[(long)N_NODES * D_FEAT + (long)node * D_FEAT + lane] = pprd;
    }

    // overflow tail (empty in practice; correct if not)
    int novf = W[WS_OVFC];
    if (novf > 0) {
        __syncthreads();
        for (int k = wave; k < novf; k += 8) {
            int d = W[WS_OVF + 2 * k];
            if ((d >> BSHIFT) == b) {
                int s = W[WS_OVF + 2 * k + 1];
                float2 f = __half22float2(packed[s * D_FEAT + lane]);
                atomicAdd(out + (long)d * D_FEAT + lane, f.x);
                unsigned int* ua =
                    (unsigned int*)(out + (long)N_NODES * D_FEAT + (long)d * D_FEAT + lane);
                unsigned int old = __hip_atomic_load(ua, __ATOMIC_RELAXED,
                                                     __HIP_MEMORY_SCOPE_AGENT);
                while (true) {
                    unsigned int assumed = old;
                    unsigned int desired =
                        __float_as_uint(__uint_as_float(assumed) * f.y);
                    old = atomicCAS(ua, assumed, desired);
                    if (old == assumed) break;
                }
            }
        }
    }
}

// ---------------- atomic fallback path, used only if ws is too small ----------------
__device__ inline void atomicMulF32(float* addr, float val) {
    unsigned int* ua = (unsigned int*)addr;
    unsigned int old = __hip_atomic_load(ua, __ATOMIC_RELAXED, __HIP_MEMORY_SCOPE_AGENT);
    while (true) {
        unsigned int assumed = old;
        unsigned int desired = __float_as_uint(__uint_as_float(assumed) * val);
        old = atomicCAS(ua, assumed, desired);
        if (old == assumed) break;
    }
}

__global__ void fb_init(float* __restrict__ out, int* __restrict__ flag,
                        const int* __restrict__ idx) {
    const int n4 = (N_NODES * D_FEAT) / 4;
    int tid = blockIdx.x * blockDim.x + threadIdx.x;
    int stride = gridDim.x * blockDim.x;
    float4* o = (float4*)out;
    const float4 z = make_float4(0.f, 0.f, 0.f, 0.f);
    const float4 one = make_float4(1.f, 1.f, 1.f, 1.f);
    for (int i = tid; i < n4; i += stride) { o[i] = z; o[n4 + i] = one; }
    if (blockIdx.x == 0 && threadIdx.x == 0) detect_idx_layout(idx, flag);
}

__global__ void fb_scatter(const float* __restrict__ xs, const float* __restrict__ xp,
                           const int* __restrict__ idx, float* __restrict__ out,
                           const int* __restrict__ flag) {
    long tid = (long)blockIdx.x * blockDim.x + threadIdx.x;
    const long total = (long)N_EDGES * (D_FEAT / 4);
    if (tid >= total) return;
    int e = (int)(tid >> 4);
    int c = (int)(tid & 15);
    int src, dst;
    if (*flag) { src = idx[2 * e]; dst = idx[2 * (N_EDGES + e)]; }
    else       { src = idx[e];     dst = idx[N_EDGES + e]; }
    const float4 s = ((const float4*)(xs + (long)src * D_FEAT))[c];
    const float4 p = ((const float4*)(xp + (long)src * D_FEAT))[c];
    float* os = out + (long)dst * D_FEAT + c * 4;
    float* op = out + (long)N_NODES * D_FEAT + (long)dst * D_FEAT + c * 4;
    atomicAdd(os + 0, s.x); atomicAdd(os + 1, s.y);
    atomicAdd(os + 2, s.z); atomicAdd(os + 3, s.w);
    atomicMulF32(op + 0, p.x); atomicMulF32(op + 1, p.y);
    atomicMulF32(op + 2, p.z); atomicMulF32(op + 3, p.w);
}

extern "C" void kernel_launch(void* const* d_in, const int* in_sizes, int n_in,
                              void* d_out, int out_size, void* d_ws, size_t ws_size,
                              hipStream_t stream) {
    const float* x_sum  = (const float*)d_in[0];
    const float* x_prod = (const float*)d_in[1];
    const int*   eidx   = (const int*)d_in[2];
    float* out = (float*)d_out;
    int* W = (int*)d_ws;

    if (ws_size < (size_t)WS_INTS * sizeof(int)) {
        fb_init<<<1024, 256, 0, stream>>>(out, W, eidx);
        const long total = (long)N_EDGES * (D_FEAT / 4);
        int grid = (int)((total + 255) / 256);
        fb_scatter<<<grid, 256, 0, stream>>>(x_sum, x_prod, eidx, out, W);
        return;
    }

    // zero padded bucket counters + overflow counter (~50 KB)
    hipMemsetAsync(W, 0, (size_t)(WS_OVFC + 16) * sizeof(int), stream);
    front<<<K1_NB, K1_TH, 0, stream>>>(W, eidx, x_sum, x_prod);
    sort_gather<<<NBKT, 512, 0, stream>>>(W, out);
}

// Round 12
// 138.679 us; speedup vs baseline: 1.0974x; 1.0081x over previous
//
#include <hip/hip_runtime.h>
#include <hip/hip_fp16.h>

#define N_NODES 50000
#define N_EDGES 800000
#define D_FEAT  64
#define BSHIFT  6
#define NBKT    782               // ceil(50000/64) buckets of 64 nodes
#define PSHIFT  16                // src < 50000 < 2^16 -> 16-bit src field
#define SRC_MASK ((1 << PSHIFT) - 1)
#define BCAP    2048              // fixed PAIR slots per bucket; load ~ Poisson(1024)

// K1 config: 391 blocks x 512 threads (R10: doubling blocks was WORSE)
#define K1_NB    391
#define K1_TH    512
#define K1_CHUNK 2047
// TOT counters padded to one cacheline to avoid same-line atomic serialization
#define TOTSTRIDE 16

// ---------- workspace layout (ints) ----------
#define WS_TOT    0                               // padded bucket counters [NBKT*16]
#define WS_OVFC   (NBKT * TOTSTRIDE)              // overflow counter [1] (+pad)
#define WS_PAIR   (WS_OVFC + 16)                  // fixed regions [NBKT*BCAP]
#define WS_OVF    (WS_PAIR + NBKT * BCAP)         // overflow (dst,src) [2*N_EDGES]
#define WS_PACKED (WS_OVF + 2 * N_EDGES)          // __half2[N_NODES*D_FEAT]
#define WS_INTS   (WS_PACKED + N_NODES * D_FEAT)

__device__ inline void detect_idx_layout(const int* idx, int* flag) {
    int allzero = 1;
    #pragma unroll
    for (int i = 1; i < 129; i += 2) {
        if (idx[i] != 0) allzero = 0;
    }
    *flag = allzero;
}

// ============ K1: fused pack + hist + claim + clustered scatter (R4-proven) ============
__global__ __launch_bounds__(K1_TH) void front(int* __restrict__ W,
                                               const int* __restrict__ idx,
                                               const float* __restrict__ xs,
                                               const float* __restrict__ xp) {
    __shared__ int h[NBKT];          // hist -> claim base -> scatter cursor
    __shared__ int flg_s;
    const int t = threadIdx.x;
    for (int i = t; i < NBKT; i += K1_TH) h[i] = 0;
    if (t == 0) flg_s = 1;
    __syncthreads();
    if (t < 128 && idx[2 * t + 1] != 0) flg_s = 0;   // parallel int64 detect
    __syncthreads();
    const int flg = flg_s;

    // stash this block's edges in registers + LDS bucket hist
    const int ebase = blockIdx.x * K1_CHUNK;
    const int eend  = min(ebase + K1_CHUNK, N_EDGES);
    int src_r[4], dst_r[4];
    #pragma unroll
    for (int i = 0; i < 4; ++i) {
        int e = ebase + t + i * K1_TH;
        bool v = (e < eend);
        int s = 0, d = 0;
        if (v) {
            if (flg) {
                s = ((const int2*)idx)[e].x;
                d = ((const int2*)idx)[N_EDGES + e].x;
            } else {
                s = idx[e];
                d = idx[N_EDGES + e];
            }
            atomicAdd(&h[d >> BSHIFT], 1);
        }
        src_r[i] = v ? s : -1;
        dst_r[i] = d;
    }

    // pack features fp16-interleaved (independent work; overlaps hist latency)
    {
        const float4* xs4 = (const float4*)xs;
        const float4* xp4 = (const float4*)xp;
        uint4* pk4 = (uint4*)(W + WS_PACKED);
        const int gtid = blockIdx.x * K1_TH + t;
        for (int g = gtid; g < (N_NODES * D_FEAT) / 4; g += K1_NB * K1_TH) {
            float4 a = xs4[g], p = xp4[g];
            union { __half2 h2; unsigned int u; } c0, c1, c2, c3;
            c0.h2 = __floats2half2_rn(a.x, p.x);
            c1.h2 = __floats2half2_rn(a.y, p.y);
            c2.h2 = __floats2half2_rn(a.z, p.z);
            c3.h2 = __floats2half2_rn(a.w, p.w);
            pk4[g] = make_uint4(c0.u, c1.u, c2.u, c3.u);
        }
    }
    __syncthreads();

    // claim contiguous within-bucket ranges (padded counters: 1 line each)
    for (int j = t; j < NBKT; j += K1_TH) {
        int c = h[j];
        h[j] = (c > 0) ? atomicAdd(&W[WS_TOT + j * TOTSTRIDE], c) : 0;
    }
    __syncthreads();

    // scatter from regs into fixed bucket regions — clustered writes
    #pragma unroll
    for (int i = 0; i < 4; ++i) {
        if (src_r[i] >= 0) {
            int d = dst_r[i];
            int bkt = d >> BSHIFT;
            int pos = atomicAdd(&h[bkt], 1);
            if (pos < BCAP) {
                W[WS_PAIR + bkt * BCAP + pos] = src_r[i] | ((d & 63) << PSHIFT);
            } else {                 // statistically unreachable; fully correct
                int op = atomicAdd(&W[WS_OVFC], 1);
                W[WS_OVF + 2 * op]     = d;
                W[WS_OVF + 2 * op + 1] = src_r[i];
            }
        }
    }
}

// ============ K2: 1024-bin (dstlow,src-top4) LDS sort + src-ordered gather ============
// Sorting each node's edges by src makes all waves sweep the feature table in
// ascending-src lockstep: the XCD-instantaneous working set is ~1/16 of 12.8MB
// (~0.8MB) -> L2-resident -> L2 miss traffic (R8: ~103MB) collapses.
__global__ __launch_bounds__(512) void sort_gather(const int* __restrict__ W,
                                                   float* __restrict__ out) {
    __shared__ int pair_l[BCAP];     // 8 KB
    __shared__ int ssrc_l[BCAP];     // 8 KB
    __shared__ int h1024[1024];      // 4 KB: bin = dstlow*16 + (src>>12)
    __shared__ int noff[65];
    const int b = blockIdx.x;
    const int t = threadIdx.x;
    const int nedge = min(W[WS_TOT + b * TOTSTRIDE], BCAP);
    const int pbase = WS_PAIR + b * BCAP;

    for (int i = t; i < 1024; i += 512) h1024[i] = 0;
    __syncthreads();
    for (int e = t; e < nedge; e += 512) {
        int v = W[pbase + e];
        pair_l[e] = v;
        int bin = (((unsigned)v >> PSHIFT) << 4) | ((v & SRC_MASK) >> 12);
        atomicAdd(&h1024[bin], 1);
    }
    __syncthreads();
    // scan 1024 bins: wave 0, 16 bins/lane; node n == lane n's first-bin offset
    if (t < 64) {
        int vals[16];
        int sum = 0;
        const int base = t << 4;
        #pragma unroll
        for (int j = 0; j < 16; ++j) { vals[j] = h1024[base + j]; sum += vals[j]; }
        int incl = sum;
        #pragma unroll
        for (int off = 1; off < 64; off <<= 1) {
            int u = __shfl_up(incl, off, 64);
            if (t >= off) incl += u;
        }
        int run = incl - sum;
        noff[t] = run;                   // start of node t's edges
        if (t == 63) noff[64] = incl;    // == nedge
        #pragma unroll
        for (int j = 0; j < 16; ++j) { h1024[base + j] = run; run += vals[j]; }
    }
    __syncthreads();
    for (int e = t; e < nedge; e += 512) {
        int v = pair_l[e];
        int bin = (((unsigned)v >> PSHIFT) << 4) | ((v & SRC_MASK) >> 12);
        int p = atomicAdd(&h1024[bin], 1);
        ssrc_l[p] = v & SRC_MASK;
    }
    __syncthreads();

    const __half2* packed = (const __half2*)(W + WS_PACKED);
    const int wave = t >> 6;
    const int lane = t & 63;
    for (int nn = wave; nn < 64; nn += 8) {
        const int node = (b << BSHIFT) + nn;
        if (node >= N_NODES) break;      // tail of bucket 781 only; nn monotone
        int beg = __builtin_amdgcn_readfirstlane(noff[nn]);
        int end = __builtin_amdgcn_readfirstlane(noff[nn + 1]);

        float s0 = 0.f, s1 = 0.f, s2 = 0.f, s3 = 0.f;
        float s4 = 0.f, s5 = 0.f, s6 = 0.f, s7 = 0.f;
        float p0 = 1.f, p1 = 1.f, p2 = 1.f, p3 = 1.f;
        float p4 = 1.f, p5 = 1.f, p6 = 1.f, p7 = 1.f;
        int i = beg;
        for (; i + 7 < end; i += 8) {
            int a0 = ssrc_l[i],     a1 = ssrc_l[i + 1];
            int a2 = ssrc_l[i + 2], a3 = ssrc_l[i + 3];
            int a4 = ssrc_l[i + 4], a5 = ssrc_l[i + 5];
            int a6 = ssrc_l[i + 6], a7 = ssrc_l[i + 7];
            float2 f0 = __half22float2(packed[a0 * D_FEAT + lane]);
            float2 f1 = __half22float2(packed[a1 * D_FEAT + lane]);
            float2 f2 = __half22float2(packed[a2 * D_FEAT + lane]);
            float2 f3 = __half22float2(packed[a3 * D_FEAT + lane]);
            float2 f4 = __half22float2(packed[a4 * D_FEAT + lane]);
            float2 f5 = __half22float2(packed[a5 * D_FEAT + lane]);
            float2 f6 = __half22float2(packed[a6 * D_FEAT + lane]);
            float2 f7 = __half22float2(packed[a7 * D_FEAT + lane]);
            s0 += f0.x; s1 += f1.x; s2 += f2.x; s3 += f3.x;
            s4 += f4.x; s5 += f5.x; s6 += f6.x; s7 += f7.x;
            p0 *= f0.y; p1 *= f1.y; p2 *= f2.y; p3 *= f3.y;
            p4 *= f4.y; p5 *= f5.y; p6 *= f6.y; p7 *= f7.y;
        }
        for (; i + 1 < end; i += 2) {
            int a0 = ssrc_l[i], a1 = ssrc_l[i + 1];
            float2 f0 = __half22float2(packed[a0 * D_FEAT + lane]);
            float2 f1 = __half22float2(packed[a1 * D_FEAT + lane]);
            s0 += f0.x; s1 += f1.x;
            p0 *= f0.y; p1 *= f1.y;
        }
        if (i < end) {
            float2 f = __half22float2(packed[ssrc_l[i] * D_FEAT + lane]);
            s0 += f.x;
            p0 *= f.y;
        }
        float ssum = ((s0 + s1) + (s2 + s3)) + ((s4 + s5) + (s6 + s7));
        float pprd = ((p0 * p1) * (p2 * p3)) * ((p4 * p5) * (p6 * p7));
        out[(long)node * D_FEAT + lane] = ssum;
        out[(long)N_NODES * D_FEAT + (long)node * D_FEAT + lane] = pprd;
    }

    // overflow tail (empty in practice; correct if not)
    int novf = W[WS_OVFC];
    if (novf > 0) {
        __syncthreads();
        for (int k = wave; k < novf; k += 8) {
            int d = W[WS_OVF + 2 * k];
            if ((d >> BSHIFT) == b) {
                int s = W[WS_OVF + 2 * k + 1];
                float2 f = __half22float2(packed[s * D_FEAT + lane]);
                atomicAdd(out + (long)d * D_FEAT + lane, f.x);
                unsigned int* ua =
                    (unsigned int*)(out + (long)N_NODES * D_FEAT + (long)d * D_FEAT + lane);
                unsigned int old = __hip_atomic_load(ua, __ATOMIC_RELAXED,
                                                     __HIP_MEMORY_SCOPE_AGENT);
                while (true) {
                    unsigned int assumed = old;
                    unsigned int desired =
                        __float_as_uint(__uint_as_float(assumed) * f.y);
                    old = atomicCAS(ua, assumed, desired);
                    if (old == assumed) break;
                }
            }
        }
    }
}

// ---------------- atomic fallback path, used only if ws is too small ----------------
__device__ inline void atomicMulF32(float* addr, float val) {
    unsigned int* ua = (unsigned int*)addr;
    unsigned int old = __hip_atomic_load(ua, __ATOMIC_RELAXED, __HIP_MEMORY_SCOPE_AGENT);
    while (true) {
        unsigned int assumed = old;
        unsigned int desired = __float_as_uint(__uint_as_float(assumed) * val);
        old = atomicCAS(ua, assumed, desired);
        if (old == assumed) break;
    }
}

__global__ void fb_init(float* __restrict__ out, int* __restrict__ flag,
                        const int* __restrict__ idx) {
    const int n4 = (N_NODES * D_FEAT) / 4;
    int tid = blockIdx.x * blockDim.x + threadIdx.x;
    int stride = gridDim.x * blockDim.x;
    float4* o = (float4*)out;
    const float4 z = make_float4(0.f, 0.f, 0.f, 0.f);
    const float4 one = make_float4(1.f, 1.f, 1.f, 1.f);
    for (int i = tid; i < n4; i += stride) { o[i] = z; o[n4 + i] = one; }
    if (blockIdx.x == 0 && threadIdx.x == 0) detect_idx_layout(idx, flag);
}

__global__ void fb_scatter(const float* __restrict__ xs, const float* __restrict__ xp,
                           const int* __restrict__ idx, float* __restrict__ out,
                           const int* __restrict__ flag) {
    long tid = (long)blockIdx.x * blockDim.x + threadIdx.x;
    const long total = (long)N_EDGES * (D_FEAT / 4);
    if (tid >= total) return;
    int e = (int)(tid >> 4);
    int c = (int)(tid & 15);
    int src, dst;
    if (*flag) { src = idx[2 * e]; dst = idx[2 * (N_EDGES + e)]; }
    else       { src = idx[e];     dst = idx[N_EDGES + e]; }
    const float4 s = ((const float4*)(xs + (long)src * D_FEAT))[c];
    const float4 p = ((const float4*)(xp + (long)src * D_FEAT))[c];
    float* os = out + (long)dst * D_FEAT + c * 4;
    float* op = out + (long)N_NODES * D_FEAT + (long)dst * D_FEAT + c * 4;
    atomicAdd(os + 0, s.x); atomicAdd(os + 1, s.y);
    atomicAdd(os + 2, s.z); atomicAdd(os + 3, s.w);
    atomicMulF32(op + 0, p.x); atomicMulF32(op + 1, p.y);
    atomicMulF32(op + 2, p.z); atomicMulF32(op + 3, p.w);
}

extern "C" void kernel_launch(void* const* d_in, const int* in_sizes, int n_in,
                              void* d_out, int out_size, void* d_ws, size_t ws_size,
                              hipStream_t stream) {
    const float* x_sum  = (const float*)d_in[0];
    const float* x_prod = (const float*)d_in[1];
    const int*   eidx   = (const int*)d_in[2];
    float* out = (float*)d_out;
    int* W = (int*)d_ws;

    if (ws_size < (size_t)WS_INTS * sizeof(int)) {
        fb_init<<<1024, 256, 0, stream>>>(out, W, eidx);
        const long total = (long)N_EDGES * (D_FEAT / 4);
        int grid = (int)((total + 255) / 256);
        fb_scatter<<<grid, 256, 0, stream>>>(x_sum, x_prod, eidx, out, W);
        return;
    }

    // zero padded bucket counters + overflow counter (~50 KB)
    hipMemsetAsync(W, 0, (size_t)(WS_OVFC + 16) * sizeof(int), stream);
    front<<<K1_NB, K1_TH, 0, stream>>>(W, eidx, x_sum, x_prod);
    sort_gather<<<NBKT, 512, 0, stream>>>(W, out);
}